// Round 4
// baseline (518.000 us; speedup 1.0000x reference)
//
#include <hip/hip_runtime.h>

// Problem constants (match reference setup_inputs)
#define N_TOTAL   524288   // TOTAL_FEATS
#define B_ROWS    16384    // B
#define FACTORS   64
#define NFEAT     1024

// Phase-1 tiling
#define BM 128             // batch rows per block
#define BF 128             // features per block
#define LDS_PAD 132        // MUST be multiple of 4: float4 LDS reads at k*PAD+tb
                           // need 16B alignment (129 would misalign odd k rows)

__global__ void zero_out_kernel(float* out) {
    out[0] = 0.0f;
}

// ---- Phase 1: C[b][f] = dot(H[user[b]], G[f]) ----
// Dense 16384x1024: 2.1 GFLOP fp32 (~14us VALU) + 64MB C write + ~26MB H
// gather (L3-resident after first touch). K is NOT folded here: only ~3%
// of C cells are consumed, so a dense 64MB K read loses to a per-entry
// sparse K gather (~34MB of touched lines) in phase 2.
__global__ __launch_bounds__(256, 2) void dense_c_kernel(
    const int*   __restrict__ user,   // [B_ROWS]
    const float* __restrict__ H,      // [NUM_USERS, FACTORS]
    const float* __restrict__ G,      // [NFEAT, FACTORS]
    float*       __restrict__ C,      // [B_ROWS, NFEAT] workspace
    float*       __restrict__ out)    // zeroed here (before phase 2 runs)
{
    if (blockIdx.x == 0 && threadIdx.x == 0) out[0] = 0.0f;

    // Transposed tiles: sHT[k][b], sGT[k][f] so compute reads are float4.
    __shared__ float sHT[FACTORS * LDS_PAD];  // 33 KB
    __shared__ float sGT[FACTORS * LDS_PAD];  // 33 KB

    const int t  = threadIdx.x;
    const int bb = (int)(blockIdx.x >> 3) * BM;   // 128 b-blocks
    const int bf = (int)(blockIdx.x & 7)  * BF;   // 8 f-blocks

    // Stage: i -> (row = i>>4, slot = i&15). 16 consecutive lanes share a row
    // -> one contiguous 256B H/G row per 16 lanes (coalesced, 4 rows/wave).
    // user[bb+row] is read by 16 lanes at once -> broadcast.
    for (int i = t; i < BM * (FACTORS / 4); i += 256) {
        const int row  = i >> 4;       // 0..127
        const int slot = i & 15;       // k = slot*4 .. slot*4+3

        const int u = user[bb + row];
        const float4 h = *(const float4*)(H + (long)u * FACTORS + slot * 4);
        sHT[(slot * 4 + 0) * LDS_PAD + row] = h.x;
        sHT[(slot * 4 + 1) * LDS_PAD + row] = h.y;
        sHT[(slot * 4 + 2) * LDS_PAD + row] = h.z;
        sHT[(slot * 4 + 3) * LDS_PAD + row] = h.w;

        const float4 g = *(const float4*)(G + (long)(bf + row) * FACTORS + slot * 4);
        sGT[(slot * 4 + 0) * LDS_PAD + row] = g.x;
        sGT[(slot * 4 + 1) * LDS_PAD + row] = g.y;
        sGT[(slot * 4 + 2) * LDS_PAD + row] = g.z;
        sGT[(slot * 4 + 3) * LDS_PAD + row] = g.w;
    }
    __syncthreads();

    // 8x8 register tile per thread: b in [tb, tb+8), f in [tf, tf+8)
    const int tb = (t >> 4) * 8;
    const int tf = (t & 15) * 8;

    float acc[8][8] = {};

    #pragma unroll 4
    for (int k = 0; k < FACTORS; ++k) {
        float a[8], bv[8];
        *(float4*)&a[0]  = *(const float4*)&sHT[k * LDS_PAD + tb];
        *(float4*)&a[4]  = *(const float4*)&sHT[k * LDS_PAD + tb + 4];
        *(float4*)&bv[0] = *(const float4*)&sGT[k * LDS_PAD + tf];
        *(float4*)&bv[4] = *(const float4*)&sGT[k * LDS_PAD + tf + 4];
        #pragma unroll
        for (int i = 0; i < 8; ++i)
            #pragma unroll
            for (int j = 0; j < 8; ++j)
                acc[i][j] = fmaf(a[i], bv[j], acc[i][j]);
    }

    // Write C tile: two float4 stores per output row (coalesced; lands in
    // L2/L3 for phase 2's gather).
    #pragma unroll
    for (int i = 0; i < 8; ++i) {
        float* cp = C + (long)(bb + tb + i) * NFEAT + (bf + tf);
        *(float4*)(cp)     = make_float4(acc[i][0], acc[i][1],
                                         acc[i][2], acc[i][3]);
        *(float4*)(cp + 4) = make_float4(acc[i][4], acc[i][5],
                                         acc[i][6], acc[i][7]);
    }
}

// ---- Phase 2: sum_i K[u_i][f_i] * C[b_i][f_i] ----
// Latency-bound gathers: C from L2/L3-resident 64MB workspace, K random
// 4B over 409MB HBM (NT-load: lines are used once, don't evict C).
// 1024 blocks -> 4 blocks/CU -> 16 waves/CU for latency hiding.
__global__ __launch_bounds__(256) void gather_sum_kernel(
    const int*   __restrict__ user,
    const int*   __restrict__ sample_idx,
    const int*   __restrict__ feat_idx,
    const float* __restrict__ K,
    const float* __restrict__ C,
    float*       __restrict__ out)
{
    const int base = (blockIdx.x * 256 + threadIdx.x) * 2;  // exact cover

    const int2 bs = *(const int2*)(sample_idx + base);
    const int2 fs = *(const int2*)(feat_idx + base);
    const int  u0 = user[bs.x];
    const int  u1 = user[bs.y];

    // Issue all 4 gathers independently, then combine.
    const float k0 = __builtin_nontemporal_load(K + (long)u0 * NFEAT + fs.x);
    const float k1 = __builtin_nontemporal_load(K + (long)u1 * NFEAT + fs.y);
    const float c0 = C[(long)bs.x * NFEAT + fs.x];
    const float c1 = C[(long)bs.y * NFEAT + fs.y];

    float local = fmaf(k0, c0, k1 * c1);

    // wave reduction (wave = 64)
    #pragma unroll
    for (int off = 32; off > 0; off >>= 1)
        local += __shfl_down(local, off, 64);

    __shared__ float smem[4];
    const int lane = threadIdx.x & 63;
    const int wave = threadIdx.x >> 6;
    if (lane == 0) smem[wave] = local;
    __syncthreads();

    if (threadIdx.x == 0)
        atomicAdd(out, smem[0] + smem[1] + smem[2] + smem[3]);
}

// ---------------- Fallback (original single-pass kernel) ----------------
__global__ __launch_bounds__(256) void kgflex_gather_kernel(
    const int*   __restrict__ user,
    const int*   __restrict__ sample_idx,
    const int*   __restrict__ feat_idx,
    const float* __restrict__ H,
    const float* __restrict__ G,
    const float* __restrict__ K,
    float*       __restrict__ out)
{
    const int tid    = blockIdx.x * blockDim.x + threadIdx.x;
    const int stride = gridDim.x * blockDim.x;

    float local = 0.0f;
    for (int i = tid; i < N_TOTAL; i += stride) {
        const int b = sample_idx[i];
        const int f = feat_idx[i];
        const int u = user[b];
        const float4* hp = (const float4*)(H + (long)u * FACTORS);
        const float4* gp = (const float4*)(G + (long)f * FACTORS);
        float acc = 0.0f;
        #pragma unroll
        for (int k = 0; k < FACTORS / 4; ++k) {
            const float4 h = hp[k];
            const float4 g = gp[k];
            acc += h.x * g.x + h.y * g.y + h.z * g.z + h.w * g.w;
        }
        local += K[(long)u * NFEAT + f] * acc;
    }
    #pragma unroll
    for (int off = 32; off > 0; off >>= 1)
        local += __shfl_down(local, off, 64);
    __shared__ float smem[4];
    const int lane = threadIdx.x & 63;
    const int wave = threadIdx.x >> 6;
    if (lane == 0) smem[wave] = local;
    __syncthreads();
    if (threadIdx.x == 0)
        atomicAdd(out, smem[0] + smem[1] + smem[2] + smem[3]);
}

extern "C" void kernel_launch(void* const* d_in, const int* in_sizes, int n_in,
                              void* d_out, int out_size, void* d_ws, size_t ws_size,
                              hipStream_t stream) {
    const int*   user       = (const int*)d_in[0];
    const int*   sample_idx = (const int*)d_in[1];
    const int*   feat_idx   = (const int*)d_in[2];
    const float* H          = (const float*)d_in[3];
    const float* G          = (const float*)d_in[4];
    const float* K          = (const float*)d_in[5];
    float* out = (float*)d_out;

    const size_t c_bytes = (size_t)B_ROWS * NFEAT * sizeof(float);  // 64 MB

    if (ws_size >= c_bytes) {
        float* C = (float*)d_ws;
        // dense_c zeroes out[0] (harness poisons d_out before every launch)
        dense_c_kernel<<<(B_ROWS / BM) * (NFEAT / BF), 256, 0, stream>>>(
            user, H, G, C, out);
        gather_sum_kernel<<<N_TOTAL / (256 * 2), 256, 0, stream>>>(
            user, sample_idx, feat_idx, K, C, out);
    } else {
        // Workspace too small — fall back to single-pass gather kernel.
        zero_out_kernel<<<1, 1, 0, stream>>>(out);
        kgflex_gather_kernel<<<2048, 256, 0, stream>>>(
            user, sample_idx, feat_idx, H, G, K, out);
    }
}

// Round 5
// 497.146 us; speedup vs baseline: 1.0419x; 1.0419x over previous
//
#include <hip/hip_runtime.h>

// Problem constants (match reference setup_inputs)
#define N_TOTAL   524288   // TOTAL_FEATS
#define FACTORS   64
#define NFEAT     1024

// MEASURED (round 4 rocprof): dur_us is dominated by 2x ~247us harness
// fillBufferAligned dispatches (1.6GB workspace poison each, 82% HBM peak)
// = ~494us fixed floor. Kernel-side marginal time is only ~20-25us.
// => minimize kernel time; avoid workspace entirely (its use bought nothing
// and the poison happens regardless).

__global__ void zero_out_kernel(float* out) {
    out[0] = 0.0f;
}

// Cooperative single-pass gather:
//   sum_i K[u_i][f_i] * dot(H[u_i], G[f_i])
// Each 16-lane group owns one entry: lane slot s in [0,16) loads float4
// #s of H[u] and G[f] rows -> the 256B row is read CONTIGUOUSLY by the
// group (full 64B-line utilization, 4 txns/row) instead of the naive
// per-thread version's 32 divergent 16B loads (25% line utilization).
// Dot finished with 4 intra-group shfl_xor steps. Two independent entry
// chains per wave-iteration for memory-level parallelism.
__global__ __launch_bounds__(256) void coop_gather_kernel(
    const int*   __restrict__ user,        // [B]
    const int*   __restrict__ sample_idx,  // [N_TOTAL]
    const int*   __restrict__ feat_idx,    // [N_TOTAL]
    const float* __restrict__ H,           // [NUM_USERS, FACTORS]
    const float* __restrict__ G,           // [NFEAT, FACTORS]
    const float* __restrict__ K,           // [NUM_USERS, NFEAT]
    float*       __restrict__ out)
{
    const int lane = threadIdx.x & 63;
    const int sub  = lane >> 4;     // 0..3  : which entry of the group of 4
    const int slot = lane & 15;     // 0..15 : float4 slot in the factor dim

    const int wid    = (blockIdx.x * 256 + threadIdx.x) >> 6;  // global wave id
    const int nwaves = (gridDim.x * 256) >> 6;                 // 4096

    float local = 0.0f;

    // 524288 = 4096 waves * 8 entries * 16 iters (exact; no bounds checks)
    for (int e8 = wid * 8; e8 < N_TOTAL; e8 += nwaves * 8) {
        // Two independent entries per 16-lane group (A and B chains)
        const int eA = e8 + sub;
        const int eB = e8 + 4 + sub;

        const int bA = sample_idx[eA];   // 16-lane broadcast loads
        const int bB = sample_idx[eB];
        const int fA = feat_idx[eA];
        const int fB = feat_idx[eB];
        const int uA = user[bA];
        const int uB = user[bB];

        const float4 hA = *(const float4*)(H + (long)uA * FACTORS + slot * 4);
        const float4 gA = *(const float4*)(G + (long)fA * FACTORS + slot * 4);
        const float4 hB = *(const float4*)(H + (long)uB * FACTORS + slot * 4);
        const float4 gB = *(const float4*)(G + (long)fB * FACTORS + slot * 4);

        float dA = hA.x * gA.x + hA.y * gA.y + hA.z * gA.z + hA.w * gA.w;
        float dB = hB.x * gB.x + hB.y * gB.y + hB.z * gB.z + hB.w * gB.w;

        // reduce across the 16 slot lanes (masks <16 stay inside the group)
        dA += __shfl_xor(dA, 8, 64);  dB += __shfl_xor(dB, 8, 64);
        dA += __shfl_xor(dA, 4, 64);  dB += __shfl_xor(dB, 4, 64);
        dA += __shfl_xor(dA, 2, 64);  dB += __shfl_xor(dB, 2, 64);
        dA += __shfl_xor(dA, 1, 64);  dB += __shfl_xor(dB, 1, 64);

        if (slot == 0) {
            const float kA = __builtin_nontemporal_load(K + (long)uA * NFEAT + fA);
            const float kB = __builtin_nontemporal_load(K + (long)uB * NFEAT + fB);
            local += kA * dA + kB * dB;
        }
    }

    // wave reduction (wave = 64)
    #pragma unroll
    for (int off = 32; off > 0; off >>= 1)
        local += __shfl_down(local, off, 64);

    __shared__ float smem[4];
    const int wave = threadIdx.x >> 6;
    if (lane == 0) smem[wave] = local;
    __syncthreads();

    if (threadIdx.x == 0)
        atomicAdd(out, smem[0] + smem[1] + smem[2] + smem[3]);   // 1024 total
}

extern "C" void kernel_launch(void* const* d_in, const int* in_sizes, int n_in,
                              void* d_out, int out_size, void* d_ws, size_t ws_size,
                              hipStream_t stream) {
    const int*   user       = (const int*)d_in[0];
    const int*   sample_idx = (const int*)d_in[1];
    const int*   feat_idx   = (const int*)d_in[2];
    const float* H          = (const float*)d_in[3];
    const float* G          = (const float*)d_in[4];
    const float* K          = (const float*)d_in[5];
    float* out = (float*)d_out;

    // Harness poisons d_out with 0xAA before every launch — zero it first.
    zero_out_kernel<<<1, 1, 0, stream>>>(out);

    // 1024 blocks x 256 threads = 4096 waves; 16 loop iterations per wave.
    coop_gather_kernel<<<1024, 256, 0, stream>>>(
        user, sample_idx, feat_idx, H, G, K, out);
}